// Round 1
// baseline (83.463 us; speedup 1.0000x reference)
//
#include <hip/hip_runtime.h>

#define NUM_TGT 5

// Lexicographic (cost, index) compare — replicates lax.top_k stability
// (ascending cost, ascending index on ties).
__device__ __forceinline__ bool lex_less(float c1, int q1, float c2, int q2) {
    return (c1 < c2) || (c1 == c2 && q1 < q2);
}

// Insert (cv,qv) into sorted-ascending 5-list held in registers (static idx only).
__device__ __forceinline__ void insert5(float c[5], int q[5], float cv, int qv) {
    if (lex_less(cv, qv, c[4], q[4])) {
        c[4] = cv; q[4] = qv;
#pragma unroll
        for (int i = 3; i >= 0; --i) {
            if (lex_less(c[i + 1], q[i + 1], c[i], q[i])) {
                float tc = c[i]; c[i] = c[i + 1]; c[i + 1] = tc;
                int   tq = q[i]; q[i] = q[i + 1]; q[i + 1] = tq;
            }
        }
    }
}

__global__ __launch_bounds__(320)
void hungarian_match_kernel(const float* __restrict__ pred_regs,   // [bs][nq][3]
                            const float* __restrict__ tgt_reg,     // [bs*5][3]
                            int* __restrict__ out,                 // rows[bs][5] ++ cols[bs][5]
                            int nq, int bs) {
    const int b    = blockIdx.x;
    const int tid  = threadIdx.x;
    const int wave = tid >> 6;   // 0..4 == target index within batch
    const int lane = tid & 63;

    __shared__ float top_c[NUM_TGT][NUM_TGT];
    __shared__ int   top_q[NUM_TGT][NUM_TGT];
    __shared__ float red_t[NUM_TGT];
    __shared__ int   red_k[NUM_TGT];

    // ---------------- Phase A: per-target top-5 (cost, query) ----------------
    {
        const int t = wave;
        const float t0 = tgt_reg[(b * NUM_TGT + t) * 3 + 0];
        const float t1 = tgt_reg[(b * NUM_TGT + t) * 3 + 1];
        const float t2 = tgt_reg[(b * NUM_TGT + t) * 3 + 2];

        float c[5] = {INFINITY, INFINITY, INFINITY, INFINITY, INFINITY};
        int   q[5] = {0x7fffffff, 0x7fffffff, 0x7fffffff, 0x7fffffff, 0x7fffffff};

        const float* base = pred_regs + (size_t)b * nq * 3;
        for (int j = 0; j * 64 + lane < nq; ++j) {
            const int qi = j * 64 + lane;
            // fp32 sum order matches jnp.sum over last axis: (|d0|+|d1|)+|d2|
            float cost = fabsf(base[qi * 3 + 0] - t0);
            cost = cost + fabsf(base[qi * 3 + 1] - t1);
            cost = cost + fabsf(base[qi * 3 + 2] - t2);
            cost = cost + 1.0f;   // COST_REG*cost_reg + COST_CLASS
            insert5(c, q, cost, qi);
        }

        // Butterfly merge across the wave: after 6 steps every lane holds the
        // wave-global top-5. Merge = insert the partner's sorted 5 one-by-one
        // (static indexing only; both partners converge to the identical list
        // because all (cost,idx) keys are distinct by idx).
#pragma unroll
        for (int m = 1; m < 64; m <<= 1) {
#pragma unroll
            for (int i = 0; i < 5; ++i) {
                float oc = __shfl_xor(c[i], m, 64);
                int   oq = __shfl_xor(q[i], m, 64);
                insert5(c, q, oc, oq);
            }
        }

        if (lane == 0) {
#pragma unroll
            for (int i = 0; i < 5; ++i) { top_c[t][i] = c[i]; top_q[t][i] = q[i]; }
        }
    }
    __syncthreads();

    // ---------------- Phase B: enumerate 5^5 tuples, lexicographic argmin ----
    float bt = INFINITY;
    int   bk = 0x7fffffff;
    for (int k = tid; k < 3125; k += 320) {
        int r  = k;
        const int d0 = r / 625; r -= d0 * 625;
        const int d1 = r / 125; r -= d1 * 125;
        const int d2 = r / 25;  r -= d2 * 25;
        const int d3 = r / 5;
        const int d4 = r - d3 * 5;

        const int q0 = top_q[0][d0], q1 = top_q[1][d1], q2 = top_q[2][d2],
                  q3 = top_q[3][d3], q4 = top_q[4][d4];
        const bool valid =
            q0 != q1 && q0 != q2 && q0 != q3 && q0 != q4 &&
            q1 != q2 && q1 != q3 && q1 != q4 &&
            q2 != q3 && q2 != q4 &&
            q3 != q4;

        // total summed t=0..4 sequentially, matching cand_c.sum(-1)
        float tot = top_c[0][d0];
        tot = tot + top_c[1][d1];
        tot = tot + top_c[2][d2];
        tot = tot + top_c[3][d3];
        tot = tot + top_c[4][d4];
        if (!valid) tot = INFINITY;

        if (tot < bt || (tot == bt && k < bk)) { bt = tot; bk = k; }
    }

    // wave-level lexicographic min-reduce
#pragma unroll
    for (int off = 32; off; off >>= 1) {
        float ot = __shfl_down(bt, off, 64);
        int   ok = __shfl_down(bk, off, 64);
        if (ot < bt || (ot == bt && ok < bk)) { bt = ot; bk = ok; }
    }
    if (lane == 0) { red_t[wave] = bt; red_k[wave] = bk; }
    __syncthreads();

    // ---------------- Final: decode best tuple, argsort rows, write ----------
    if (tid == 0) {
        float fbt = red_t[0]; int fbk = red_k[0];
#pragma unroll
        for (int w = 1; w < NUM_TGT; ++w) {
            if (red_t[w] < fbt || (red_t[w] == fbt && red_k[w] < fbk)) {
                fbt = red_t[w]; fbk = red_k[w];
            }
        }
        int r = fbk;
        int d[5];
        d[0] = r / 625; r -= d[0] * 625;
        d[1] = r / 125; r -= d[1] * 125;
        d[2] = r / 25;  r -= d[2] * 25;
        d[3] = r / 5;
        d[4] = r - d[3] * 5;

        int rows[5];
#pragma unroll
        for (int t = 0; t < 5; ++t) rows[t] = top_q[t][d[t]];

        // order = argsort(rows); rows are distinct for a valid tuple.
        // out[0:bs*5]       = rows[order]  (sorted ascending)
        // out[bs*5:2*bs*5]  = order
#pragma unroll
        for (int i = 0; i < 5; ++i) {
            int rank = 0;
#pragma unroll
            for (int j = 0; j < 5; ++j) rank += (rows[j] < rows[i]);
            out[b * 5 + rank]          = rows[i];
            out[bs * 5 + b * 5 + rank] = i;
        }
    }
}

extern "C" void kernel_launch(void* const* d_in, const int* in_sizes, int n_in,
                              void* d_out, int out_size, void* d_ws, size_t ws_size,
                              hipStream_t stream) {
    // inputs: [0] pred_logits (bs*nq) fp32 (UNUSED), [1] pred_regs (bs*nq*3) fp32,
    //         [2] labels (bs*5) int32 (UNUSED), [3] tgt_regression (bs*5*3) fp32
    const float* pred_regs = (const float*)d_in[1];
    const float* tgt_reg   = (const float*)d_in[3];
    int* out = (int*)d_out;

    const int T  = in_sizes[2];       // bs * NUM_TGT
    const int bs = T / NUM_TGT;
    const int nq = in_sizes[0] / bs;  // pred_logits is (bs, nq, 1)

    hungarian_match_kernel<<<bs, 320, 0, stream>>>(pred_regs, tgt_reg, out, nq, bs);
}

// Round 2
// 75.263 us; speedup vs baseline: 1.1089x; 1.1089x over previous
//
#include <hip/hip_runtime.h>

#define NUM_TGT 5

// Lexicographic (cost, index) compare — replicates lax.top_k stability
// (ascending cost, ascending index on ties).
__device__ __forceinline__ bool lex_less(float c1, int q1, float c2, int q2) {
    return (c1 < c2) || (c1 == c2 && q1 < q2);
}

// Insert (cv,qv) into sorted-ascending 5-list held in registers (static idx only).
__device__ __forceinline__ void insert5(float c[5], int q[5], float cv, int qv) {
    if (lex_less(cv, qv, c[4], q[4])) {
        c[4] = cv; q[4] = qv;
#pragma unroll
        for (int i = 3; i >= 0; --i) {
            if (lex_less(c[i + 1], q[i + 1], c[i], q[i])) {
                float tc = c[i]; c[i] = c[i + 1]; c[i + 1] = tc;
                int   tq = q[i]; q[i] = q[i + 1]; q[i + 1] = tq;
            }
        }
    }
}

// ---------------------------------------------------------------------------
// Kernel 1: one block per (batch, target). 256 threads; each lane handles 8
// queries. Produces the per-target top-5 (cost, query) list, written to ws.
// ws layout: top_c[bs*5*5] floats ++ top_q[bs*5*5] ints.
// ---------------------------------------------------------------------------
__global__ __launch_bounds__(256)
void topk_kernel(const float* __restrict__ pred_regs,   // [bs][nq][3]
                 const float* __restrict__ tgt_reg,     // [bs*5][3]
                 float* __restrict__ ws_c,              // [bs*5][5]
                 int* __restrict__ ws_q,                // [bs*5][5]
                 int nq) {
    const int bt   = blockIdx.x;          // b*5 + t
    const int b    = bt / NUM_TGT;
    const int tid  = threadIdx.x;
    const int wave = tid >> 6;            // 0..3
    const int lane = tid & 63;

    __shared__ float wc[4][NUM_TGT];
    __shared__ int   wq[4][NUM_TGT];

    const float t0 = tgt_reg[bt * 3 + 0];
    const float t1 = tgt_reg[bt * 3 + 1];
    const float t2 = tgt_reg[bt * 3 + 2];

    float c[5] = {INFINITY, INFINITY, INFINITY, INFINITY, INFINITY};
    int   q[5] = {0x7fffffff, 0x7fffffff, 0x7fffffff, 0x7fffffff, 0x7fffffff};

    const float* base = pred_regs + (size_t)b * nq * 3;
#pragma unroll
    for (int j = 0; j < 8; ++j) {
        const int qi = j * 256 + tid;
        if (qi < nq) {
            // fp32 sum order matches jnp.sum over last axis: (|d0|+|d1|)+|d2|
            float cost = fabsf(base[qi * 3 + 0] - t0);
            cost = cost + fabsf(base[qi * 3 + 1] - t1);
            cost = cost + fabsf(base[qi * 3 + 2] - t2);
            cost = cost + 1.0f;   // COST_REG*cost_reg + COST_CLASS
            insert5(c, q, cost, qi);
        }
    }

    // Butterfly merge across the wave: after 6 steps every lane holds the
    // wave-global top-5 (keys (cost,idx) are distinct by idx, so all lanes
    // converge to the identical list).
#pragma unroll
    for (int m = 1; m < 64; m <<= 1) {
#pragma unroll
        for (int i = 0; i < 5; ++i) {
            float oc = __shfl_xor(c[i], m, 64);
            int   oq = __shfl_xor(q[i], m, 64);
            insert5(c, q, oc, oq);
        }
    }

    if (lane == 0) {
#pragma unroll
        for (int i = 0; i < 5; ++i) { wc[wave][i] = c[i]; wq[wave][i] = q[i]; }
    }
    __syncthreads();

    // Cross-wave merge (3 lists of 5 into wave 0's list) on one thread; tiny.
    if (tid == 0) {
#pragma unroll
        for (int w = 1; w < 4; ++w)
#pragma unroll
            for (int i = 0; i < 5; ++i)
                insert5(c, q, wc[w][i], wq[w][i]);
#pragma unroll
        for (int i = 0; i < 5; ++i) {
            ws_c[bt * NUM_TGT + i] = c[i];
            ws_q[bt * NUM_TGT + i] = q[i];
        }
    }
}

// ---------------------------------------------------------------------------
// Kernel 2: one block per batch. Enumerate 5^5 tuples, lexicographic argmin
// on (total, candidate-index), decode, argsort rows, write output.
// ---------------------------------------------------------------------------
__global__ __launch_bounds__(256)
void enumerate_kernel(const float* __restrict__ ws_c,   // [bs*5][5]
                      const int* __restrict__ ws_q,     // [bs*5][5]
                      int* __restrict__ out,            // rows[bs][5] ++ cols[bs][5]
                      int bs) {
    const int b    = blockIdx.x;
    const int tid  = threadIdx.x;
    const int wave = tid >> 6;
    const int lane = tid & 63;

    __shared__ float top_c[NUM_TGT][NUM_TGT];
    __shared__ int   top_q[NUM_TGT][NUM_TGT];
    __shared__ float red_t[4];
    __shared__ int   red_k[4];

    if (tid < 25) {
        top_c[tid / 5][tid % 5] = ws_c[b * 25 + tid];
        top_q[tid / 5][tid % 5] = ws_q[b * 25 + tid];
    }
    __syncthreads();

    float bt = INFINITY;
    int   bk = 0x7fffffff;
    for (int k = tid; k < 3125; k += 256) {
        int r  = k;
        const int d0 = r / 625; r -= d0 * 625;
        const int d1 = r / 125; r -= d1 * 125;
        const int d2 = r / 25;  r -= d2 * 25;
        const int d3 = r / 5;
        const int d4 = r - d3 * 5;

        const int q0 = top_q[0][d0], q1 = top_q[1][d1], q2 = top_q[2][d2],
                  q3 = top_q[3][d3], q4 = top_q[4][d4];
        const bool valid =
            q0 != q1 && q0 != q2 && q0 != q3 && q0 != q4 &&
            q1 != q2 && q1 != q3 && q1 != q4 &&
            q2 != q3 && q2 != q4 &&
            q3 != q4;

        // total summed t=0..4 sequentially, matching cand_c.sum(-1)
        float tot = top_c[0][d0];
        tot = tot + top_c[1][d1];
        tot = tot + top_c[2][d2];
        tot = tot + top_c[3][d3];
        tot = tot + top_c[4][d4];
        if (!valid) tot = INFINITY;

        if (tot < bt || (tot == bt && k < bk)) { bt = tot; bk = k; }
    }

    // wave-level lexicographic min-reduce
#pragma unroll
    for (int off = 32; off; off >>= 1) {
        float ot = __shfl_down(bt, off, 64);
        int   ok = __shfl_down(bk, off, 64);
        if (ot < bt || (ot == bt && ok < bk)) { bt = ot; bk = ok; }
    }
    if (lane == 0) { red_t[wave] = bt; red_k[wave] = bk; }
    __syncthreads();

    if (tid == 0) {
        float fbt = red_t[0]; int fbk = red_k[0];
#pragma unroll
        for (int w = 1; w < 4; ++w) {
            if (red_t[w] < fbt || (red_t[w] == fbt && red_k[w] < fbk)) {
                fbt = red_t[w]; fbk = red_k[w];
            }
        }
        int r = fbk;
        int d[5];
        d[0] = r / 625; r -= d[0] * 625;
        d[1] = r / 125; r -= d[1] * 125;
        d[2] = r / 25;  r -= d[2] * 25;
        d[3] = r / 5;
        d[4] = r - d[3] * 5;

        int rows[5];
#pragma unroll
        for (int t = 0; t < 5; ++t) rows[t] = top_q[t][d[t]];

        // order = argsort(rows); rows are distinct for a valid tuple.
#pragma unroll
        for (int i = 0; i < 5; ++i) {
            int rank = 0;
#pragma unroll
            for (int j = 0; j < 5; ++j) rank += (rows[j] < rows[i]);
            out[b * 5 + rank]          = rows[i];
            out[bs * 5 + b * 5 + rank] = i;
        }
    }
}

extern "C" void kernel_launch(void* const* d_in, const int* in_sizes, int n_in,
                              void* d_out, int out_size, void* d_ws, size_t ws_size,
                              hipStream_t stream) {
    // inputs: [0] pred_logits (bs*nq) fp32 (UNUSED), [1] pred_regs (bs*nq*3) fp32,
    //         [2] labels (bs*5) int32 (UNUSED), [3] tgt_regression (bs*5*3) fp32
    const float* pred_regs = (const float*)d_in[1];
    const float* tgt_reg   = (const float*)d_in[3];
    int* out = (int*)d_out;

    const int T  = in_sizes[2];       // bs * NUM_TGT
    const int bs = T / NUM_TGT;
    const int nq = in_sizes[0] / bs;  // pred_logits is (bs, nq, 1)

    // ws: top_c [bs*5*5] floats ++ top_q [bs*5*5] ints
    float* ws_c = (float*)d_ws;
    int*   ws_q = (int*)(ws_c + (size_t)bs * NUM_TGT * NUM_TGT);

    topk_kernel<<<bs * NUM_TGT, 256, 0, stream>>>(pred_regs, tgt_reg, ws_c, ws_q, nq);
    enumerate_kernel<<<bs, 256, 0, stream>>>(ws_c, ws_q, out, bs);
}